// Round 1
// baseline (133.619 us; speedup 1.0000x reference)
//
#include <hip/hip_runtime.h>
#include <math.h>

#define BB 16
#define NN 96
#define HH 256
#define NBIN 11

// ---------------------------------------------------------------------------
// Kernel 1: proj[r][k] = sum_h inputs[r][h] * W_atom[h][k] + 0.5*b_bin[k]
//   r = b*N + i  (B*N = 1536 rows). 8 rows per block so W_atom (256 KB) is
//   read only 192x total (~49 MB, L2-resident).
// ---------------------------------------------------------------------------
#define ROWS_PER_BLOCK 8

__global__ __launch_bounds__(HH) void proj_kernel(
    const float* __restrict__ inputs,
    const float* __restrict__ W_atom,
    const float* __restrict__ b_bin,
    float* __restrict__ proj)
{
    __shared__ float rows[ROWS_PER_BLOCK][HH];
    const int r0 = blockIdx.x * ROWS_PER_BLOCK;
    const int k  = threadIdx.x;

    #pragma unroll
    for (int r = 0; r < ROWS_PER_BLOCK; ++r)
        rows[r][k] = inputs[(size_t)(r0 + r) * HH + k];
    __syncthreads();

    float acc[ROWS_PER_BLOCK];
    #pragma unroll
    for (int r = 0; r < ROWS_PER_BLOCK; ++r) acc[r] = 0.f;

    for (int h = 0; h < HH; ++h) {
        const float w = W_atom[(size_t)h * HH + k];   // coalesced over k
        #pragma unroll
        for (int r = 0; r < ROWS_PER_BLOCK; ++r)
            acc[r] = fmaf(rows[r][h], w, acc[r]);     // LDS broadcast read
    }

    const float halfb = 0.5f * b_bin[k];
    #pragma unroll
    for (int r = 0; r < ROWS_PER_BLOCK; ++r)
        proj[(size_t)(r0 + r) * HH + k] = acc[r] + halfb;
}

// ---------------------------------------------------------------------------
// Kernel 2: one block per (b,i,j) pair p = (b*N+i)*N + j, 256 threads (k).
//   - writes atom_pair[p][k] = inputs[b,i,k] + inputs[b,j,k]  (151 MB, the
//     dominant HBM traffic)
//   - hidden_k = relu(proj[bi][k] + proj[bj][k] + sum_c bin[p][c]*W_bin[c][k])
//     (b_bin already folded into proj)
//   - score[p] = sigmoid(sum_k hidden_k * w_score[k] + b_score)
// ---------------------------------------------------------------------------
__global__ __launch_bounds__(HH) void pair_kernel(
    const float* __restrict__ inputs,
    const float* __restrict__ bin_features,
    const float* __restrict__ W_bin,
    const float* __restrict__ w_score,
    const float* __restrict__ b_score,
    const float* __restrict__ proj,
    float* __restrict__ atom_pair,
    float* __restrict__ score)
{
    const int p  = blockIdx.x;          // 0 .. B*N*N-1
    const int j  = p % NN;
    const int bi = p / NN;              // b*N + i
    const int b  = bi / NN;
    const int bj = b * NN + j;
    const int k  = threadIdx.x;

    __shared__ float binf[NBIN];
    if (k < NBIN) binf[k] = bin_features[(size_t)p * NBIN + k];
    __syncthreads();

    const float in_i = inputs[(size_t)bi * HH + k];
    const float in_j = inputs[(size_t)bj * HH + k];
    atom_pair[(size_t)p * HH + k] = in_i + in_j;

    float v = proj[(size_t)bi * HH + k] + proj[(size_t)bj * HH + k];
    #pragma unroll
    for (int c = 0; c < NBIN; ++c)
        v = fmaf(binf[c], W_bin[c * HH + k], v);
    v = fmaxf(v, 0.f);

    float t = v * w_score[k];
    #pragma unroll
    for (int off = 32; off > 0; off >>= 1)
        t += __shfl_down(t, off, 64);

    __shared__ float partial[4];
    if ((k & 63) == 0) partial[k >> 6] = t;
    __syncthreads();
    if (k == 0) {
        const float s = partial[0] + partial[1] + partial[2] + partial[3]
                        + b_score[0];
        score[p] = 1.f / (1.f + expf(-s));
    }
}

// ---------------------------------------------------------------------------
// Kernel 3: context[bi][h] = sum_j score[bi][j] * inputs[b*N+j][h]
//   One block per bi (1536 blocks), 256 threads (h). inputs[b] is 98 KB ->
//   L2-resident across the 96 blocks sharing it.
// ---------------------------------------------------------------------------
__global__ __launch_bounds__(HH) void context_kernel(
    const float* __restrict__ inputs,
    const float* __restrict__ score,
    float* __restrict__ context)
{
    const int bi = blockIdx.x;          // b*N + i
    const int b  = bi / NN;
    const int h  = threadIdx.x;

    __shared__ float s[NN];
    if (h < NN) s[h] = score[(size_t)bi * NN + h];
    __syncthreads();

    float acc = 0.f;
    #pragma unroll 4
    for (int jj = 0; jj < NN; ++jj)
        acc = fmaf(s[jj], inputs[(size_t)(b * NN + jj) * HH + h], acc);

    context[(size_t)bi * HH + h] = acc;
}

extern "C" void kernel_launch(void* const* d_in, const int* in_sizes, int n_in,
                              void* d_out, int out_size, void* d_ws, size_t ws_size,
                              hipStream_t stream)
{
    const float* inputs       = (const float*)d_in[0];   // (B,N,H)
    const float* bin_features = (const float*)d_in[1];   // (B,N,N,BIN)
    const float* W_atom       = (const float*)d_in[2];   // (H,H)
    const float* W_bin        = (const float*)d_in[3];   // (BIN,H)
    const float* b_bin        = (const float*)d_in[4];   // (H,)
    const float* w_score      = (const float*)d_in[5];   // (H,1)
    const float* b_score      = (const float*)d_in[6];   // (1,)

    float* context   = (float*)d_out;                         // B*N*H
    float* atom_pair = (float*)d_out + (size_t)BB * NN * HH;  // B*N*N*H

    float* proj  = (float*)d_ws;                              // B*N*H floats
    float* score = proj + (size_t)BB * NN * HH;               // B*N*N floats

    proj_kernel<<<(BB * NN) / ROWS_PER_BLOCK, HH, 0, stream>>>(
        inputs, W_atom, b_bin, proj);

    pair_kernel<<<BB * NN * NN, HH, 0, stream>>>(
        inputs, bin_features, W_bin, w_score, b_score, proj,
        atom_pair, score);

    context_kernel<<<BB * NN, HH, 0, stream>>>(inputs, score, context);
}

// Round 2
// 70.670 us; speedup vs baseline: 1.8907x; 1.8907x over previous
//
#include <hip/hip_runtime.h>
#include <math.h>

#define BB 16
#define NN 96
#define HH 256
#define NBIN 11

// ---------------------------------------------------------------------------
// Kernel 1: proj[r][k] = sum_h inputs[r][h] * W_atom[h][k] + 0.5*b_bin[k]
// ---------------------------------------------------------------------------
#define ROWS_PER_BLOCK 8

__global__ __launch_bounds__(HH) void proj_kernel(
    const float* __restrict__ inputs,
    const float* __restrict__ W_atom,
    const float* __restrict__ b_bin,
    float* __restrict__ proj)
{
    __shared__ float rows[ROWS_PER_BLOCK][HH];
    const int r0 = blockIdx.x * ROWS_PER_BLOCK;
    const int k  = threadIdx.x;

    #pragma unroll
    for (int r = 0; r < ROWS_PER_BLOCK; ++r)
        rows[r][k] = inputs[(size_t)(r0 + r) * HH + k];
    __syncthreads();

    float acc[ROWS_PER_BLOCK];
    #pragma unroll
    for (int r = 0; r < ROWS_PER_BLOCK; ++r) acc[r] = 0.f;

    for (int h = 0; h < HH; ++h) {
        const float w = W_atom[(size_t)h * HH + k];   // coalesced over k
        #pragma unroll
        for (int r = 0; r < ROWS_PER_BLOCK; ++r)
            acc[r] = fmaf(rows[r][h], w, acc[r]);     // LDS broadcast read
    }

    const float halfb = 0.5f * b_bin[k];
    #pragma unroll
    for (int r = 0; r < ROWS_PER_BLOCK; ++r)
        proj[(size_t)(r0 + r) * HH + k] = acc[r] + halfb;
}

// ---------------------------------------------------------------------------
// Kernel 2: one block per (b,i) row; 4 waves; each wave owns j = wave+4*it.
//   lane*4 indexes H via float4 (64 lanes x 4 = 256 = H).
//   Per j: atom_pair store (float4), hidden = relu(proj_i+proj_j+bin.W_bin),
//   score = sigmoid(<hidden,w_score>+b) via intra-wave shfl reduce.
//   No LDS, no __syncthreads.
// ---------------------------------------------------------------------------
__global__ __launch_bounds__(256) void pair_kernel(
    const float* __restrict__ inputs,
    const float* __restrict__ bin_features,
    const float* __restrict__ W_bin,
    const float* __restrict__ w_score,
    const float* __restrict__ b_score,
    const float* __restrict__ proj,
    float* __restrict__ atom_pair,
    float* __restrict__ score)
{
    const int bi   = blockIdx.x;           // b*N + i
    const int b    = bi / NN;
    const int lane = threadIdx.x & 63;
    const int wave = threadIdx.x >> 6;     // 0..3
    const int k4   = lane << 2;            // float4 offset into H

    const float4 in_i = *(const float4*)(inputs + (size_t)bi * HH + k4);
    const float4 pr_i = *(const float4*)(proj   + (size_t)bi * HH + k4);
    const float4 ws   = *(const float4*)(w_score + k4);
    const float  bsc  = b_score[0];

    float4 wb[NBIN];
    #pragma unroll
    for (int c = 0; c < NBIN; ++c)
        wb[c] = *(const float4*)(W_bin + c * HH + k4);

    for (int j = wave; j < NN; j += 4) {
        const int    bj = b * NN + j;
        const size_t p  = (size_t)bi * NN + j;

        const float4 in_j = *(const float4*)(inputs + (size_t)bj * HH + k4);
        const float4 pr_j = *(const float4*)(proj   + (size_t)bj * HH + k4);

        float4 ap;
        ap.x = in_i.x + in_j.x;  ap.y = in_i.y + in_j.y;
        ap.z = in_i.z + in_j.z;  ap.w = in_i.w + in_j.w;
        *(float4*)(atom_pair + p * HH + k4) = ap;

        float bin[NBIN];
        const float* bp = bin_features + p * NBIN;
        #pragma unroll
        for (int c = 0; c < NBIN; ++c) bin[c] = bp[c];

        float4 v;
        v.x = pr_i.x + pr_j.x;  v.y = pr_i.y + pr_j.y;
        v.z = pr_i.z + pr_j.z;  v.w = pr_i.w + pr_j.w;
        #pragma unroll
        for (int c = 0; c < NBIN; ++c) {
            v.x = fmaf(bin[c], wb[c].x, v.x);
            v.y = fmaf(bin[c], wb[c].y, v.y);
            v.z = fmaf(bin[c], wb[c].z, v.z);
            v.w = fmaf(bin[c], wb[c].w, v.w);
        }
        v.x = fmaxf(v.x, 0.f); v.y = fmaxf(v.y, 0.f);
        v.z = fmaxf(v.z, 0.f); v.w = fmaxf(v.w, 0.f);

        float t = v.x * ws.x + v.y * ws.y + v.z * ws.z + v.w * ws.w;
        #pragma unroll
        for (int off = 32; off > 0; off >>= 1)
            t += __shfl_xor(t, off, 64);

        if (lane == 0)
            score[p] = 1.f / (1.f + expf(-(t + bsc)));
    }
}

// ---------------------------------------------------------------------------
// Kernel 3: context[bi][h] = sum_j score[bi][j] * inputs[b*N+j][h]
//   One block per bi, 64 lanes x float4 over H; 4 waves split j and
//   combine through LDS.
// ---------------------------------------------------------------------------
__global__ __launch_bounds__(256) void context_kernel(
    const float* __restrict__ inputs,
    const float* __restrict__ score,
    float* __restrict__ context)
{
    const int bi   = blockIdx.x;
    const int b    = bi / NN;
    const int lane = threadIdx.x & 63;
    const int wave = threadIdx.x >> 6;
    const int k4   = lane << 2;

    __shared__ float s[NN];
    if (threadIdx.x < NN) s[threadIdx.x] = score[(size_t)bi * NN + threadIdx.x];
    __shared__ float partial[3][HH];
    __syncthreads();

    float4 acc = make_float4(0.f, 0.f, 0.f, 0.f);
    for (int j = wave; j < NN; j += 4) {
        const float sc = s[j];
        const float4 in_j =
            *(const float4*)(inputs + (size_t)(b * NN + j) * HH + k4);
        acc.x = fmaf(sc, in_j.x, acc.x);
        acc.y = fmaf(sc, in_j.y, acc.y);
        acc.z = fmaf(sc, in_j.z, acc.z);
        acc.w = fmaf(sc, in_j.w, acc.w);
    }

    if (wave > 0) *(float4*)(&partial[wave - 1][k4]) = acc;
    __syncthreads();
    if (wave == 0) {
        #pragma unroll
        for (int w = 0; w < 3; ++w) {
            const float4 pw = *(const float4*)(&partial[w][k4]);
            acc.x += pw.x; acc.y += pw.y; acc.z += pw.z; acc.w += pw.w;
        }
        *(float4*)(context + (size_t)bi * HH + k4) = acc;
    }
}

extern "C" void kernel_launch(void* const* d_in, const int* in_sizes, int n_in,
                              void* d_out, int out_size, void* d_ws, size_t ws_size,
                              hipStream_t stream)
{
    const float* inputs       = (const float*)d_in[0];   // (B,N,H)
    const float* bin_features = (const float*)d_in[1];   // (B,N,N,BIN)
    const float* W_atom       = (const float*)d_in[2];   // (H,H)
    const float* W_bin        = (const float*)d_in[3];   // (BIN,H)
    const float* b_bin        = (const float*)d_in[4];   // (H,)
    const float* w_score      = (const float*)d_in[5];   // (H,1)
    const float* b_score      = (const float*)d_in[6];   // (1,)

    float* context   = (float*)d_out;                         // B*N*H
    float* atom_pair = (float*)d_out + (size_t)BB * NN * HH;  // B*N*N*H

    float* proj  = (float*)d_ws;                              // B*N*H floats
    float* score = proj + (size_t)BB * NN * HH;               // B*N*N floats

    proj_kernel<<<(BB * NN) / ROWS_PER_BLOCK, HH, 0, stream>>>(
        inputs, W_atom, b_bin, proj);

    pair_kernel<<<BB * NN, 256, 0, stream>>>(
        inputs, bin_features, W_bin, w_score, b_score, proj,
        atom_pair, score);

    context_kernel<<<BB * NN, 256, 0, stream>>>(inputs, score, context);
}

// Round 4
// 64.115 us; speedup vs baseline: 2.0840x; 1.1022x over previous
//
#include <hip/hip_runtime.h>
#include <math.h>

#define BB 16
#define NN 96
#define HH 256
#define NBIN 11

typedef float f32x4 __attribute__((ext_vector_type(4)));

// ---------------------------------------------------------------------------
// Kernel 1: proj[r][k] = sum_h inputs[r][h] * W_atom[h][k] + 0.5*b_bin[k]
// ---------------------------------------------------------------------------
#define ROWS_PER_BLOCK 8

__global__ __launch_bounds__(HH) void proj_kernel(
    const float* __restrict__ inputs,
    const float* __restrict__ W_atom,
    const float* __restrict__ b_bin,
    float* __restrict__ proj)
{
    __shared__ float rows[ROWS_PER_BLOCK][HH];
    const int r0 = blockIdx.x * ROWS_PER_BLOCK;
    const int k  = threadIdx.x;

    #pragma unroll
    for (int r = 0; r < ROWS_PER_BLOCK; ++r)
        rows[r][k] = inputs[(size_t)(r0 + r) * HH + k];
    __syncthreads();

    float acc[ROWS_PER_BLOCK];
    #pragma unroll
    for (int r = 0; r < ROWS_PER_BLOCK; ++r) acc[r] = 0.f;

    for (int h = 0; h < HH; ++h) {
        const float w = W_atom[(size_t)h * HH + k];   // coalesced over k
        #pragma unroll
        for (int r = 0; r < ROWS_PER_BLOCK; ++r)
            acc[r] = fmaf(rows[r][h], w, acc[r]);     // LDS broadcast read
    }

    const float halfb = 0.5f * b_bin[k];
    #pragma unroll
    for (int r = 0; r < ROWS_PER_BLOCK; ++r)
        proj[(size_t)(r0 + r) * HH + k] = acc[r] + halfb;
}

// ---------------------------------------------------------------------------
// Kernel 2 (fused pair + context): one block per (b,i); 4 waves; wave owns
//   j = wave + 4*it. lane*4 indexes H via float4.
//   Per j: atom_pair nontemporal store; hidden = relu(proj_i+proj_j+bin.Wb);
//   butterfly shfl_xor leaves the full dot sum in EVERY lane -> all lanes
//   compute s = sigmoid(sum+b) and fuse acc += s*in_j (context) for free.
//   End: cross-wave LDS reduce of acc -> context[bi].
//   bin_features for this bi is 96*11 floats = 4224 B CONTIGUOUS -> staged
//   cooperatively into LDS once (ideal fetch), then broadcast-read.
// ---------------------------------------------------------------------------
__global__ __launch_bounds__(256) void pair_ctx_kernel(
    const float* __restrict__ inputs,
    const float* __restrict__ bin_features,
    const float* __restrict__ W_bin,
    const float* __restrict__ w_score,
    const float* __restrict__ b_score,
    const float* __restrict__ proj,
    float* __restrict__ atom_pair,
    float* __restrict__ context)
{
    const int bi   = blockIdx.x;           // b*N + i
    const int b    = bi / NN;
    const int lane = threadIdx.x & 63;
    const int wave = threadIdx.x >> 6;     // 0..3
    const int k4   = lane << 2;            // float4 offset into H

    __shared__ float binf[NN * NBIN];      // 4224 B, contiguous block of bin
    __shared__ float partial[3][HH];

    {
        const float* bp = bin_features + (size_t)bi * NN * NBIN;
        for (int t = threadIdx.x; t < NN * NBIN; t += 256)
            binf[t] = bp[t];
    }

    const float4 in_i = *(const float4*)(inputs + (size_t)bi * HH + k4);
    const float4 pr_i = *(const float4*)(proj   + (size_t)bi * HH + k4);
    const float4 ws   = *(const float4*)(w_score + k4);
    const float  bsc  = b_score[0];

    float4 wb[NBIN];
    #pragma unroll
    for (int c = 0; c < NBIN; ++c)
        wb[c] = *(const float4*)(W_bin + c * HH + k4);

    __syncthreads();                       // binf ready

    float4 acc = make_float4(0.f, 0.f, 0.f, 0.f);

    for (int j = wave; j < NN; j += 4) {
        const int    bj = b * NN + j;
        const size_t p  = (size_t)bi * NN + j;

        const float4 in_j = *(const float4*)(inputs + (size_t)bj * HH + k4);
        const float4 pr_j = *(const float4*)(proj   + (size_t)bj * HH + k4);

        f32x4 ap;
        ap.x = in_i.x + in_j.x;  ap.y = in_i.y + in_j.y;
        ap.z = in_i.z + in_j.z;  ap.w = in_i.w + in_j.w;
        __builtin_nontemporal_store(ap, (f32x4*)(atom_pair + p * HH + k4));

        float4 v;
        v.x = pr_i.x + pr_j.x;  v.y = pr_i.y + pr_j.y;
        v.z = pr_i.z + pr_j.z;  v.w = pr_i.w + pr_j.w;
        const float* bf = &binf[j * NBIN];
        #pragma unroll
        for (int c = 0; c < NBIN; ++c) {
            const float bc = bf[c];        // LDS broadcast (same addr/wave)
            v.x = fmaf(bc, wb[c].x, v.x);
            v.y = fmaf(bc, wb[c].y, v.y);
            v.z = fmaf(bc, wb[c].z, v.z);
            v.w = fmaf(bc, wb[c].w, v.w);
        }
        v.x = fmaxf(v.x, 0.f); v.y = fmaxf(v.y, 0.f);
        v.z = fmaxf(v.z, 0.f); v.w = fmaxf(v.w, 0.f);

        float t = v.x * ws.x + v.y * ws.y + v.z * ws.z + v.w * ws.w;
        #pragma unroll
        for (int off = 32; off > 0; off >>= 1)
            t += __shfl_xor(t, off, 64);   // full sum in every lane

        const float s = 1.f / (1.f + expf(-(t + bsc)));
        acc.x = fmaf(s, in_j.x, acc.x);
        acc.y = fmaf(s, in_j.y, acc.y);
        acc.z = fmaf(s, in_j.z, acc.z);
        acc.w = fmaf(s, in_j.w, acc.w);
    }

    // cross-wave reduce of context accumulator
    if (wave > 0) *(float4*)(&partial[wave - 1][k4]) = acc;
    __syncthreads();
    if (wave == 0) {
        #pragma unroll
        for (int w = 0; w < 3; ++w) {
            const float4 pw = *(const float4*)(&partial[w][k4]);
            acc.x += pw.x; acc.y += pw.y; acc.z += pw.z; acc.w += pw.w;
        }
        *(float4*)(context + (size_t)bi * HH + k4) = acc;
    }
}

extern "C" void kernel_launch(void* const* d_in, const int* in_sizes, int n_in,
                              void* d_out, int out_size, void* d_ws, size_t ws_size,
                              hipStream_t stream)
{
    const float* inputs       = (const float*)d_in[0];   // (B,N,H)
    const float* bin_features = (const float*)d_in[1];   // (B,N,N,BIN)
    const float* W_atom       = (const float*)d_in[2];   // (H,H)
    const float* W_bin        = (const float*)d_in[3];   // (BIN,H)
    const float* b_bin        = (const float*)d_in[4];   // (H,)
    const float* w_score      = (const float*)d_in[5];   // (H,1)
    const float* b_score      = (const float*)d_in[6];   // (1,)

    float* context   = (float*)d_out;                         // B*N*H
    float* atom_pair = (float*)d_out + (size_t)BB * NN * HH;  // B*N*N*H

    float* proj = (float*)d_ws;                               // B*N*H floats

    proj_kernel<<<(BB * NN) / ROWS_PER_BLOCK, HH, 0, stream>>>(
        inputs, W_atom, b_bin, proj);

    pair_ctx_kernel<<<BB * NN, 256, 0, stream>>>(
        inputs, bin_features, W_bin, w_score, b_score, proj,
        atom_pair, context);
}